// Round 8
// baseline (266.077 us; speedup 1.0000x reference)
//
#include <hip/hip_runtime.h>

// StochasticPool2D eval-mode: out = sum(w^2)/sum(w) over non-overlapping 2x2
// windows of relu(x); windows with zero sum produce 0.
// x: [64, 256, 112, 112] f32  ->  out: [64, 256, 56, 56] f32
//
// R7: NO LDS, NO barriers -- pure streaming. Key observation: rows are
// 28 v4f wide, so the vertical partner of v4f f is f+28. Each wave loads
// span A=[64j,64j+64) and span B=[64j+28,64j+92): BOTH are dense 1024 B
// spans. Every byte is loaded twice but the second delivery hits L1/L2
// (spans are block-contiguous, overlap never crosses XCD except 0.14% at
// block edges) -- HBM traffic stays 1x. Lanes on odd rows are inactive;
// active lanes form 28-lane runs storing 224 B contiguous v2f segments.
// out_row = r/2 globally (112 rows/plane, even) -- no plane bookkeeping.

typedef float v4f __attribute__((ext_vector_type(4)));
typedef float v2f __attribute__((ext_vector_type(2)));

#define N4     51380224u   // total input v4f  (64*256*112*112 / 4)
#define NSPAN  802816u     // N4 / 64
#define GRID   2048u
#define SPB    392u        // spans per block = NSPAN / GRID (exact)
#define WITERS 98u         // iters per wave  = SPB / 4 waves (exact, even)

__device__ __forceinline__ v2f pool_pair(v4f A, v4f B) {
    float a0 = fmaxf(A.x, 0.f), a1 = fmaxf(A.y, 0.f);
    float a2 = fmaxf(A.z, 0.f), a3 = fmaxf(A.w, 0.f);
    float b0 = fmaxf(B.x, 0.f), b1 = fmaxf(B.y, 0.f);
    float b2 = fmaxf(B.z, 0.f), b3 = fmaxf(B.w, 0.f);
    float s0 = (a0 + a1) + (b0 + b1);
    float q0 = (a0 * a0 + a1 * a1) + (b0 * b0 + b1 * b1);
    float s1 = (a2 + a3) + (b2 + b3);
    float q1 = (a2 * a2 + a3 * a3) + (b2 * b2 + b3 * b3);
    v2f o;
    o.x = (s0 > 0.f) ? q0 * __builtin_amdgcn_rcpf(s0) : 0.f;
    o.y = (s1 > 0.f) ? q1 * __builtin_amdgcn_rcpf(s1) : 0.f;
    return o;
}

__global__ __launch_bounds__(256) void stoch_pool2d_kernel(
    const float* __restrict__ in, float* __restrict__ out) {
    const v4f* in4  = reinterpret_cast<const v4f*>(in);
    v2f*       out2 = reinterpret_cast<v2f*>(out);

    unsigned int wave = threadIdx.x >> 6;
    unsigned int lane = threadIdx.x & 63u;
    // Wave w of block b handles spans b*SPB + w + 4*i  (block-contiguous
    // range; the 4 waves' spans at a given i are adjacent -> 8 KB dense
    // window per block per unrolled iter, and A/B overlap stays intra-block).
    unsigned int f = (blockIdx.x * SPB + wave) * 64u + lane;

    for (unsigned int i = 0; i < WITERS; i += 2u) {
        unsigned int f0 = f;
        unsigned int f1 = f + 256u;  // span j+4 (this wave's next span)
        unsigned int fb0 = f0 + 28u; fb0 = (fb0 < N4) ? fb0 : (N4 - 1u);
        unsigned int fb1 = f1 + 28u; fb1 = (fb1 < N4) ? fb1 : (N4 - 1u);
        // (clamped lanes are provably on odd rows -> inactive -> value unused)

        v4f A0 = __builtin_nontemporal_load(in4 + f0);
        v4f B0 = __builtin_nontemporal_load(in4 + fb0);
        v4f A1 = __builtin_nontemporal_load(in4 + f1);
        v4f B1 = __builtin_nontemporal_load(in4 + fb1);

        unsigned int r0 = f0 / 28u;  unsigned int k0 = f0 - r0 * 28u;
        unsigned int r1 = f1 / 28u;  unsigned int k1 = f1 - r1 * 28u;

        v2f o0 = pool_pair(A0, B0);
        v2f o1 = pool_pair(A1, B1);

        if (!(r0 & 1u))
            __builtin_nontemporal_store(o0, out2 + ((r0 >> 1) * 28u + k0));
        if (!(r1 & 1u))
            __builtin_nontemporal_store(o1, out2 + ((r1 >> 1) * 28u + k1));

        f += 512u;  // advance 2 spans (stride 4 spans each)
    }
}

extern "C" void kernel_launch(void* const* d_in, const int* in_sizes, int n_in,
                              void* d_out, int out_size, void* d_ws, size_t ws_size,
                              hipStream_t stream) {
    const float* x = (const float*)d_in[0];
    float* out = (float*)d_out;

    stoch_pool2d_kernel<<<GRID, 256, 0, stream>>>(x, out);
}

// Round 9
// 184.455 us; speedup vs baseline: 1.4425x; 1.4425x over previous
//
#include <hip/hip_runtime.h>

// StochasticPool2D eval-mode: out = sum(w^2)/sum(w) over non-overlapping 2x2
// windows of relu(x); windows summing to 0 produce 0.
// x: [64, 256, 112, 112] f32  ->  out: [64, 256, 56, 56] f32
//
// FINAL (= R4, best measured 183.6 us = 5.60 TB/s on the exact 1.028 GB
// footprint, ~89% of the 6.29 TB/s copy ceiling):
//  - block stages a contiguous 28 KB chunk (64 input rows) to LDS; every
//    wave-load instruction covers 1024 B dense & aligned (rows are 448 B =
//    3.5 cachelines, so any direct row-pair scheme fragments requests).
//  - nontemporal loads AND stores (ablations: NT loads +5.5% vs plain;
//    NT stores keep the write stream out of L2).
//  - register prefetch of chunk k+1 issued before chunk k's barrier.
//  - v4f output path: 4 ds_read_b128 -> 4 windows -> 1 dwordx4 NT store.
//  - grid 2048: 28672 chunks / 2048 = exactly 14 per block, no tail.
// Ablation history: raw-barrier (no vmcnt drain) null; no-LDS double-read
// regressed; ~5.6 TB/s is this 4:1 read:write mix's plateau across four
// structurally different kernels => roofline.

typedef float v4f __attribute__((ext_vector_type(4)));

#define NCHUNK 28672u
#define CH_IN  7168u   // f32 per input chunk  (64 rows x 112)
#define CH_OUT 1792u   // f32 per output chunk (32 rows x 56)
#define GRID   2048u
#define ITERS  14u     // NCHUNK / GRID, exact

__device__ __forceinline__ float pool1(float x0, float x1, float y0, float y1) {
    float a0 = fmaxf(x0, 0.f), a1 = fmaxf(x1, 0.f);
    float b0 = fmaxf(y0, 0.f), b1 = fmaxf(y1, 0.f);
    float s = (a0 + a1) + (b0 + b1);
    float q = (a0 * a0 + a1 * a1) + (b0 * b0 + b1 * b1);
    return (s > 0.f) ? q * __builtin_amdgcn_rcpf(s) : 0.f;
}

__global__ __launch_bounds__(256) void stoch_pool2d_kernel(
    const float* __restrict__ in, float* __restrict__ out) {
    __shared__ float lds[CH_IN];          // 28 KB -> 5 blocks/CU
    const unsigned int t = threadIdx.x;

    unsigned int c = blockIdx.x;

    // Prologue: load first chunk into registers.
    v4f r[7];
    {
        const v4f* src = reinterpret_cast<const v4f*>(in + (size_t)c * CH_IN);
#pragma unroll
        for (int i = 0; i < 7; ++i)
            r[i] = __builtin_nontemporal_load(src + (i * 256u + t));
    }

    for (unsigned int it = 0; it < ITERS; ++it) {
        // Drain regs -> LDS (compiler waits vmcnt per-use here).
#pragma unroll
        for (int i = 0; i < 7; ++i)
            reinterpret_cast<v4f*>(lds)[i * 256u + t] = r[i];

        // Prefetch next chunk into regs BEFORE the barrier.
        v4f nxt[7];
        if (it + 1u < ITERS) {
            const v4f* src =
                reinterpret_cast<const v4f*>(in + (size_t)(c + GRID) * CH_IN);
#pragma unroll
            for (int i = 0; i < 7; ++i)
                nxt[i] = __builtin_nontemporal_load(src + (i * 256u + t));
        }
        __syncthreads();

        // Compute: each thread-iter builds one output v4f (4 windows).
        // 448 output v4f per chunk: iter0 all 256 threads, iter1 t<192
        // (wave 3 fully idle -> no intra-wave divergence).
        float* dst = out + (size_t)c * CH_OUT;
        const v4f* l4 = reinterpret_cast<const v4f*>(lds);
#pragma unroll
        for (unsigned int i = 0; i < 2; ++i) {
            unsigned int o4 = i * 256u + t;
            if (o4 < 448u) {
                unsigned int orow = o4 / 14u;          // output row in chunk
                unsigned int oc4  = o4 - orow * 14u;   // v4f col in out row
                unsigned int base = orow * 56u + oc4 * 2u;  // v4f idx, top row
                v4f t0 = l4[base];
                v4f t1 = l4[base + 1u];
                v4f b0 = l4[base + 28u];               // +112 f32 = next row
                v4f b1 = l4[base + 29u];
                v4f v;
                v.x = pool1(t0.x, t0.y, b0.x, b0.y);
                v.y = pool1(t0.z, t0.w, b0.z, b0.w);
                v.z = pool1(t1.x, t1.y, b1.x, b1.y);
                v.w = pool1(t1.z, t1.w, b1.z, b1.w);
                __builtin_nontemporal_store(v, reinterpret_cast<v4f*>(dst) + o4);
            }
        }
        __syncthreads();  // protect LDS reuse next iteration

#pragma unroll
        for (int i = 0; i < 7; ++i) r[i] = nxt[i];
        c += GRID;
    }
}

extern "C" void kernel_launch(void* const* d_in, const int* in_sizes, int n_in,
                              void* d_out, int out_size, void* d_ws, size_t ws_size,
                              hipStream_t stream) {
    const float* x = (const float*)d_in[0];
    float* out = (float*)d_out;

    stoch_pool2d_kernel<<<GRID, 256, 0, stream>>>(x, out);
}